// Round 14
// baseline (188.230 us; speedup 1.0000x reference)
//
#include <hip/hip_runtime.h>
#include <hip/hip_bf16.h>

#define NN 50000
#define NN_PAD 50176   // 196*256 = 784*64
#define NE 800000
#define NB 196         // coarse buckets = dst>>8
#define CAP 6144       // per-bucket pair capacity (mean 4096, sd 64)
#define EPB 4096       // edges per pass-A block

typedef __attribute__((ext_vector_type(8))) short short8;
typedef __attribute__((ext_vector_type(4))) float f32x4;
typedef __attribute__((ext_vector_type(2))) float f32x2;

__device__ __forceinline__ unsigned short f2bf(float f) {
    union { float f; unsigned u; } v; v.f = f;
    unsigned u = v.u;
    return (unsigned short)((u + 0x7fffu + ((u >> 16) & 1u)) >> 16);
}
__device__ __forceinline__ float bfu_lo(unsigned u) {
    union { unsigned u; float f; } v; v.u = u << 16; return v.f;
}
__device__ __forceinline__ float bfu_hi(unsigned u) {
    union { unsigned u; float f; } v; v.u = u & 0xffff0000u; return v.f;
}

// A_pk fragment-packed layout: tile t (64 rows), element (r, k):
//   ks=k>>5, lq=(k>>3)&3, j=k&7, mi=r>>4, lm=r&15
//   index = t*16384 + ((ks*4+mi)*64 + lm + 16*lq)*8 + j

// ---- merged setup + edge-partition ----
// blocks [0,196): pass A of CSR build (two-pass, no scratch)
// blocks [196,260): pack W1/W2 into MFMA B-fragment order
// blocks [260,6510): x -> fp8 gather table + A_pk self-columns (bf16, frag-packed)
__global__ void k_setup_part(const float* __restrict__ W1l, const float* __restrict__ W1r,
                             const float* __restrict__ W2l, const float* __restrict__ W2r,
                             unsigned short* __restrict__ W1pk, unsigned short* __restrict__ W2pk,
                             const float4* __restrict__ x4, unsigned short* __restrict__ Apk,
                             unsigned char* __restrict__ x_f8,
                             const int* __restrict__ src, const int* __restrict__ dst,
                             int* __restrict__ gcursor, unsigned* __restrict__ pairs) {
    int blk = blockIdx.x, t = threadIdx.x;
    if (blk < NB) {
        __shared__ int cnt[256];
        __shared__ int cur[256];
        __shared__ int base[256];
        cnt[t] = 0; cur[t] = 0;
        __syncthreads();
        int e0 = blk * EPB;
        int eend = min(e0 + EPB, NE);
        for (int e = e0 + t; e < eend; e += 256)
            atomicAdd(&cnt[dst[e] >> 8], 1);
        __syncthreads();
        if (t < NB && cnt[t] > 0) base[t] = t * CAP + atomicAdd(&gcursor[t], cnt[t]);
        __syncthreads();
        for (int e = e0 + t; e < eend; e += 256) {
            int s = src[e], d = dst[e];
            int bk = d >> 8;
            int pos = base[bk] + atomicAdd(&cur[bk], 1);
            if (pos < (bk + 1) * CAP) pairs[pos] = ((unsigned)s << 8) | (unsigned)(d & 255);
        }
    } else if (blk < 260) {
        int tid = (blk - 196) * 256 + t;    // 0..16383
        int table = tid >> 13;              // 0: W1, 1: W2
        int r = tid & 8191;
        int lane = r & 63, ni = (r >> 6) & 3, ks = (r >> 8) & 7, g = r >> 11;
        int lm = lane & 15, lq = lane >> 4;
        int o = g * 64 + ni * 16 + lm;
        int k = ks * 32 + lq * 8;
        unsigned short v[8];
        if (table == 0) {                   // W1 = [W1l | W1r] K-concat
            if (k < 128) {
#pragma unroll
                for (int j = 0; j < 8; ++j) v[j] = f2bf(W1l[o * 128 + k + j]);
            } else {
#pragma unroll
                for (int j = 0; j < 8; ++j) v[j] = f2bf(W1r[o * 128 + k - 128 + j]);
            }
            *(uint4*)(W1pk + (size_t)r * 8) = *(const uint4*)v;
        } else {                            // W2 = [W2l ; W2r] out-stack
            if (o < 128) {
#pragma unroll
                for (int j = 0; j < 8; ++j) v[j] = f2bf(W2l[o * 256 + k + j]);
            } else {
#pragma unroll
                for (int j = 0; j < 8; ++j) v[j] = f2bf(W2r[(o - 128) * 256 + k + j]);
            }
            *(uint4*)(W2pk + (size_t)r * 8) = *(const uint4*)v;
        }
    } else {
        int gid = (blk - 260) * 256 + t;    // NN*32
        int n = gid >> 5, c = gid & 31;     // self cols k = 128 + c*4 .. +3
        float4 v = x4[(size_t)n * 32 + c];
        unsigned short o[4];
        o[0] = f2bf(v.x); o[1] = f2bf(v.y); o[2] = f2bf(v.z); o[3] = f2bf(v.w);
        int k = 128 + c * 4;
        int ks = k >> 5, lq = (k >> 3) & 3, j0 = k & 7;
        int tile = n >> 6, r = n & 63, mi = r >> 4, lm = r & 15;
        *(uint2*)(Apk + (size_t)tile * 16384 +
                  ((size_t)((ks * 4 + mi) * 64 + lm + 16 * lq)) * 8 + j0) = *(const uint2*)o;
        unsigned p = (unsigned)__builtin_amdgcn_cvt_pk_fp8_f32(v.x, v.y, 0, false);
        p = (unsigned)__builtin_amdgcn_cvt_pk_fp8_f32(v.z, v.w, (int)p, true);
        *(unsigned*)(x_f8 + (size_t)n * 128 + c * 4) = p;
    }
}

// ---- pass B: scan bucket counts + per-bucket LDS counting sort, two-pass ----
// meta[n] = row_start | (deg << 20); esrc is ushort.
__global__ void k_build(const int* __restrict__ gcursor, const unsigned* __restrict__ pairs,
                        unsigned* __restrict__ meta, unsigned short* __restrict__ esrc) {
    __shared__ int buf[256];
    __shared__ int ldeg[256];
    __shared__ int cur[256];
    __shared__ int sh_base, sh_cnt;
    __shared__ unsigned short lsrc[CAP];
    int b = blockIdx.x, t = threadIdx.x;
    int c = (t < NB) ? min(gcursor[t], CAP) : 0;
    buf[t] = c;
    __syncthreads();
#pragma unroll
    for (int o = 1; o < 256; o <<= 1) {
        int add = (t >= o) ? buf[t - o] : 0;
        __syncthreads();
        buf[t] += add;
        __syncthreads();
    }
    if (t == b) { sh_cnt = c; sh_base = buf[b] - c; }
    ldeg[t] = 0;
    __syncthreads();
    int cnt = sh_cnt, base = sh_base;
    for (int e = t; e < cnt; e += 256)
        atomicAdd(&ldeg[pairs[(size_t)b * CAP + e] & 255u], 1);
    __syncthreads();
    int v = ldeg[t];
    buf[t] = v;
    __syncthreads();
#pragma unroll
    for (int o = 1; o < 256; o <<= 1) {
        int add = (t >= o) ? buf[t - o] : 0;
        __syncthreads();
        buf[t] += add;
        __syncthreads();
    }
    int lst = buf[t] - v;
    cur[t] = lst;
    int node = b * 256 + t;
    meta[node] = (node < NN) ? ((unsigned)(base + lst) | ((unsigned)v << 20)) : 0u;
    __syncthreads();
    for (int e = t; e < cnt; e += 256) {
        unsigned p = pairs[(size_t)b * CAP + e];
        int pos = atomicAdd(&cur[p & 255u], 1);
        lsrc[pos] = (unsigned short)(p >> 8);
    }
    __syncthreads();
    for (int e = t; e < cnt; e += 256) esrc[base + e] = lsrc[e];
}

// ============ layer-1 aggregation -> A_pk cols 0..127 (fragment-packed) ============
__global__ void k_agg1(const uint2* __restrict__ xf8, const unsigned* __restrict__ meta,
                       const unsigned short* __restrict__ esrc,
                       unsigned short* __restrict__ Apk) {
    int gid = blockIdx.x * blockDim.x + threadIdx.x;  // NN*16 threads exactly
    int n = gid >> 4, c = gid & 15;                   // cols k = c*8 .. +7
    unsigned mt = meta[n];
    int st = (int)(mt & 0xFFFFFu), dg = (int)(mt >> 20);
    float acc[8] = {0.f, 0.f, 0.f, 0.f, 0.f, 0.f, 0.f, 0.f};
    int i = 0;
    for (; i + 2 <= dg; i += 2) {
        int s0 = esrc[st + i], s1 = esrc[st + i + 1];
        uint2 q0 = xf8[(size_t)s0 * 16 + c];
        uint2 q1 = xf8[(size_t)s1 * 16 + c];
        f32x2 a0 = __builtin_amdgcn_cvt_pk_f32_fp8(q0.x, false);
        f32x2 a1 = __builtin_amdgcn_cvt_pk_f32_fp8(q0.x, true);
        f32x2 a2 = __builtin_amdgcn_cvt_pk_f32_fp8(q0.y, false);
        f32x2 a3 = __builtin_amdgcn_cvt_pk_f32_fp8(q0.y, true);
        f32x2 b0 = __builtin_amdgcn_cvt_pk_f32_fp8(q1.x, false);
        f32x2 b1 = __builtin_amdgcn_cvt_pk_f32_fp8(q1.x, true);
        f32x2 b2 = __builtin_amdgcn_cvt_pk_f32_fp8(q1.y, false);
        f32x2 b3 = __builtin_amdgcn_cvt_pk_f32_fp8(q1.y, true);
        acc[0] += a0.x + b0.x; acc[1] += a0.y + b0.y;
        acc[2] += a1.x + b1.x; acc[3] += a1.y + b1.y;
        acc[4] += a2.x + b2.x; acc[5] += a2.y + b2.y;
        acc[6] += a3.x + b3.x; acc[7] += a3.y + b3.y;
    }
    if (i < dg) {
        int s = esrc[st + i];
        uint2 q0 = xf8[(size_t)s * 16 + c];
        f32x2 a0 = __builtin_amdgcn_cvt_pk_f32_fp8(q0.x, false);
        f32x2 a1 = __builtin_amdgcn_cvt_pk_f32_fp8(q0.x, true);
        f32x2 a2 = __builtin_amdgcn_cvt_pk_f32_fp8(q0.y, false);
        f32x2 a3 = __builtin_amdgcn_cvt_pk_f32_fp8(q0.y, true);
        acc[0] += a0.x; acc[1] += a0.y;
        acc[2] += a1.x; acc[3] += a1.y;
        acc[4] += a2.x; acc[5] += a2.y;
        acc[6] += a3.x; acc[7] += a3.y;
    }
    float invd = 1.0f / (float)max(dg, 1);
    unsigned short o[8];
#pragma unroll
    for (int j = 0; j < 8; ++j) o[j] = f2bf(acc[j] * invd);
    int ks = c >> 2, lq = c & 3;
    int tile = n >> 6, r = n & 63, mi = r >> 4, lm = r & 15;
    *(uint4*)(Apk + (size_t)tile * 16384 +
              ((size_t)((ks * 4 + mi) * 64 + lm + 16 * lq)) * 8) = *(const uint4*)o;
}

// ============ fused GEMM1(relu)+GEMM2 per 64-node tile, packed-A direct reads ============
// A_pk is fragment-packed: wave A-loads are 1 KB coalesced global loads (L2-hot),
// so there is NO A-staging phase and only ONE barrier (h-write -> GEMM2).
// W in VGPRs (32 short8 = 128 regs/wave, loaded once per layer).
// h LDS tile T: element (m, k) at chunk (ks*4+mi)*64 + lm*4 + lq.
__global__ __launch_bounds__(256, 2) void k_gemm12(
        const unsigned short* __restrict__ Apk,
        const unsigned short* __restrict__ W1pk, const unsigned short* __restrict__ W2pk,
        const float* __restrict__ b1, const float* __restrict__ b2,
        unsigned char* __restrict__ y2f8, unsigned short* __restrict__ Sbf) {
    __shared__ unsigned short T[16384];   // 32 KB h tile
    int t = threadIdx.x, blk = blockIdx.x;
    int wave = t >> 6, lane = t & 63;
    int lm = lane & 15, lq = lane >> 4;
    int pbase = lm * 4 + lq;

    // ---- preload W1 slice into registers ----
    short8 w[8][4];
    {
        const unsigned short* wb = W1pk + (size_t)wave * 16384;
#pragma unroll
        for (int ks = 0; ks < 8; ++ks)
#pragma unroll
            for (int ni = 0; ni < 4; ++ni)
                w[ks][ni] = *(const short8*)(wb + ((size_t)((ks * 4 + ni) * 64 + lane)) * 8);
    }

    // ---- GEMM1: A direct from packed global (coalesced), no staging/barrier ----
    const unsigned short* apk = Apk + (size_t)blk * 16384;
    f32x4 acc1[4][4];
#pragma unroll
    for (int mi = 0; mi < 4; ++mi)
#pragma unroll
        for (int ni = 0; ni < 4; ++ni) acc1[mi][ni] = (f32x4){0.f, 0.f, 0.f, 0.f};
#pragma unroll
    for (int ks = 0; ks < 8; ++ks) {
        short8 a[4];
#pragma unroll
        for (int mi = 0; mi < 4; ++mi)
            a[mi] = *(const short8*)(apk + ((size_t)((ks * 4 + mi) * 64 + lane)) * 8);
#pragma unroll
        for (int mi = 0; mi < 4; ++mi)
#pragma unroll
            for (int ni = 0; ni < 4; ++ni)
                acc1[mi][ni] = __builtin_amdgcn_mfma_f32_16x16x32_bf16(a[mi], w[ks][ni], acc1[mi][ni], 0, 0, 0);
    }

    // ---- reload registers with W2 slice (latency hidden by h-write) ----
    {
        const unsigned short* wb = W2pk + (size_t)wave * 16384;
#pragma unroll
        for (int ks = 0; ks < 8; ++ks)
#pragma unroll
            for (int ni = 0; ni < 4; ++ni)
                w[ks][ni] = *(const short8*)(wb + ((size_t)((ks * 4 + ni) * 64 + lane)) * 8);
    }

    // ---- h = relu(acc1 + b1) into T (fragment order; per-wave disjoint chunks) ----
#pragma unroll
    for (int ni = 0; ni < 4; ++ni) {
        int col = wave * 64 + ni * 16 + lm;
        float bv = b1[col];
        int ks = col >> 5;
        int la = (col & 31) >> 3, j = col & 7;
#pragma unroll
        for (int mi = 0; mi < 4; ++mi)
#pragma unroll
            for (int r = 0; r < 4; ++r) {
                float v = fmaxf(acc1[mi][ni][r] + bv, 0.0f);
                T[((size_t)((ks * 4 + mi) * 64 + (lq * 4 + r) * 4 + la)) * 8 + j] = f2bf(v);
            }
    }
    __syncthreads();   // the ONLY barrier

    // ---- GEMM2 ----
    f32x4 acc2[4][4];
#pragma unroll
    for (int mi = 0; mi < 4; ++mi)
#pragma unroll
        for (int ni = 0; ni < 4; ++ni) acc2[mi][ni] = (f32x4){0.f, 0.f, 0.f, 0.f};
#pragma unroll
    for (int ks = 0; ks < 8; ++ks) {
        short8 a[4];
#pragma unroll
        for (int mi = 0; mi < 4; ++mi)
            a[mi] = *(const short8*)(T + ((size_t)((ks * 4 + mi) * 64 + pbase)) * 8);
#pragma unroll
        for (int mi = 0; mi < 4; ++mi)
#pragma unroll
            for (int ni = 0; ni < 4; ++ni)
                acc2[mi][ni] = __builtin_amdgcn_mfma_f32_16x16x32_bf16(a[mi], w[ks][ni], acc2[mi][ni], 0, 0, 0);
    }

    // ---- epilogue: waves 0,1 -> y2f8 fp8 (cols 0..127); waves 2,3 -> Sbf = bf16(self+b2) ----
    if (wave < 2) {
#pragma unroll
        for (int ni = 0; ni < 4; ++ni) {
            int col = wave * 64 + ni * 16 + lm;
#pragma unroll
            for (int mi = 0; mi < 4; ++mi)
#pragma unroll
                for (int r = 0; r < 4; ++r) {
                    int row = blk * 64 + mi * 16 + lq * 4 + r;
                    float v = acc2[mi][ni][r];
                    unsigned p = (unsigned)__builtin_amdgcn_cvt_pk_fp8_f32(v, v, 0, false);
                    y2f8[(size_t)row * 128 + col] = (unsigned char)(p & 0xff);  // sized NN_PAD
                }
        }
    } else {
#pragma unroll
        for (int ni = 0; ni < 4; ++ni) {
            int col = (wave - 2) * 64 + ni * 16 + lm;
            float bv = b2[col];
#pragma unroll
            for (int mi = 0; mi < 4; ++mi)
#pragma unroll
                for (int r = 0; r < 4; ++r) {
                    int row = blk * 64 + mi * 16 + lq * 4 + r;
                    Sbf[(size_t)row * 128 + col] = f2bf(acc2[mi][ni][r] + bv);  // sized NN_PAD
                }
        }
    }
}

// ============ output: out[n] = Sbf[n] + mean_nbr(y2f8)  (pure write) ============
__global__ void k_agg_out(const uint2* __restrict__ yf8, const uint4* __restrict__ Sbf4,
                          const unsigned* __restrict__ meta,
                          const unsigned short* __restrict__ esrc,
                          float* __restrict__ out) {
    int gid = blockIdx.x * blockDim.x + threadIdx.x;  // NN*16 threads exactly
    int n = gid >> 4, c = gid & 15;
    unsigned mt = meta[n];
    int st = (int)(mt & 0xFFFFFu), dg = (int)(mt >> 20);
    float acc[8] = {0.f, 0.f, 0.f, 0.f, 0.f, 0.f, 0.f, 0.f};
    int i = 0;
    for (; i + 2 <= dg; i += 2) {
        int s0 = esrc[st + i], s1 = esrc[st + i + 1];
        uint2 q0 = yf8[(size_t)s0 * 16 + c];
        uint2 q1 = yf8[(size_t)s1 * 16 + c];
        f32x2 a0 = __builtin_amdgcn_cvt_pk_f32_fp8(q0.x, false);
        f32x2 a1 = __builtin_amdgcn_cvt_pk_f32_fp8(q0.x, true);
        f32x2 a2 = __builtin_amdgcn_cvt_pk_f32_fp8(q0.y, false);
        f32x2 a3 = __builtin_amdgcn_cvt_pk_f32_fp8(q0.y, true);
        f32x2 b0 = __builtin_amdgcn_cvt_pk_f32_fp8(q1.x, false);
        f32x2 b1 = __builtin_amdgcn_cvt_pk_f32_fp8(q1.x, true);
        f32x2 b2 = __builtin_amdgcn_cvt_pk_f32_fp8(q1.y, false);
        f32x2 b3 = __builtin_amdgcn_cvt_pk_f32_fp8(q1.y, true);
        acc[0] += a0.x + b0.x; acc[1] += a0.y + b0.y;
        acc[2] += a1.x + b1.x; acc[3] += a1.y + b1.y;
        acc[4] += a2.x + b2.x; acc[5] += a2.y + b2.y;
        acc[6] += a3.x + b3.x; acc[7] += a3.y + b3.y;
    }
    if (i < dg) {
        int s = esrc[st + i];
        uint2 q0 = yf8[(size_t)s * 16 + c];
        f32x2 a0 = __builtin_amdgcn_cvt_pk_f32_fp8(q0.x, false);
        f32x2 a1 = __builtin_amdgcn_cvt_pk_f32_fp8(q0.x, true);
        f32x2 a2 = __builtin_amdgcn_cvt_pk_f32_fp8(q0.y, false);
        f32x2 a3 = __builtin_amdgcn_cvt_pk_f32_fp8(q0.y, true);
        acc[0] += a0.x; acc[1] += a0.y;
        acc[2] += a1.x; acc[3] += a1.y;
        acc[4] += a2.x; acc[5] += a2.y;
        acc[6] += a3.x; acc[7] += a3.y;
    }
    float invd = 1.0f / (float)max(dg, 1);
    uint4 sv = Sbf4[(size_t)n * 16 + c];
    float4 o0, o1;
    o0.x = bfu_lo(sv.x) + acc[0] * invd; o0.y = bfu_hi(sv.x) + acc[1] * invd;
    o0.z = bfu_lo(sv.y) + acc[2] * invd; o0.w = bfu_hi(sv.y) + acc[3] * invd;
    o1.x = bfu_lo(sv.z) + acc[4] * invd; o1.y = bfu_hi(sv.z) + acc[5] * invd;
    o1.z = bfu_lo(sv.w) + acc[6] * invd; o1.w = bfu_hi(sv.w) + acc[7] * invd;
    float* op = out + (size_t)n * 128 + c * 8;
    *(float4*)op = o0; *(float4*)(op + 4) = o1;
}

extern "C" void kernel_launch(void* const* d_in, const int* in_sizes, int n_in,
                              void* d_out, int out_size, void* d_ws, size_t ws_size,
                              hipStream_t stream) {
    const float* x   = (const float*)d_in[0];
    const int*   ei  = (const int*)d_in[1];
    const int*   src = ei;
    const int*   dst = ei + NE;
    const float* W1l = (const float*)d_in[2];
    const float* b1  = (const float*)d_in[3];
    const float* W1r = (const float*)d_in[4];
    const float* W2l = (const float*)d_in[5];
    const float* b2  = (const float*)d_in[6];
    const float* W2r = (const float*)d_in[7];
    float* out = (float*)d_out;

    // workspace layout (~62 MB):
    char* ws = (char*)d_ws;
    unsigned* meta        = (unsigned*)(ws + 0);               // [NN_PAD] start|deg<<20
    int* gcursor          = (int*)(ws + 401408);               // [256]
    unsigned short* esrc  = (unsigned short*)(ws + 409600);    // [NE] ushort 1.6 MB
    unsigned* pairs       = (unsigned*)(ws + 4194304);         // [NB*CAP] 4.8 MB
    unsigned short* Sbf   = (unsigned short*)(ws + 9437184);   // [NN_PAD,128] bf16 12.85 MB
    unsigned char* x_f8   = (unsigned char*)(ws + 22282240);   // [NN,128] fp8 6.4 MB
    unsigned char* y2f8   = (unsigned char*)(ws + 28704768);   // [NN_PAD,128] fp8 6.42 MB
    unsigned short* Apk   = (unsigned short*)(ws + 35651584);  // [NN_PAD,256] bf16 frag-packed
    unsigned short* W1pk  = (unsigned short*)(ws + 61341696);  // [65536] 131 KB frag-packed
    unsigned short* W2pk  = (unsigned short*)(ws + 61472768);  // [65536] 131 KB frag-packed

    hipMemsetAsync(gcursor, 0, 1024, stream);
    k_setup_part<<<6510, 256, 0, stream>>>(W1l, W1r, W2l, W2r, W1pk, W2pk,
                                           (const float4*)x, Apk, x_f8, src, dst,
                                           gcursor, pairs);
    k_build<<<NB, 256, 0, stream>>>(gcursor, pairs, meta, esrc);
    k_agg1<<<NN * 16 / 256, 256, 0, stream>>>((const uint2*)x_f8, meta, esrc, Apk);
    k_gemm12<<<NN_PAD / 64, 256, 0, stream>>>(Apk, W1pk, W2pk, b1, b2, y2f8, Sbf);
    k_agg_out<<<NN * 16 / 256, 256, 0, stream>>>((const uint2*)y2f8, (const uint4*)Sbf,
                                                 meta, esrc, out);
}

// Round 15
// 184.998 us; speedup vs baseline: 1.0175x; 1.0175x over previous
//
#include <hip/hip_runtime.h>
#include <hip/hip_bf16.h>

#define NN 50000
#define NN_PAD 50176   // 196*256 = 784*64
#define NE 800000
#define NB 196         // coarse buckets = dst>>8
#define CAP 6144       // per-bucket pair capacity (mean 4096, sd 64)
#define EPB 4096       // edges per pass-A block

typedef __attribute__((ext_vector_type(8))) short short8;
typedef __attribute__((ext_vector_type(4))) float f32x4;
typedef __attribute__((ext_vector_type(2))) float f32x2;

__device__ __forceinline__ unsigned short f2bf(float f) {
    union { float f; unsigned u; } v; v.f = f;
    unsigned u = v.u;
    return (unsigned short)((u + 0x7fffu + ((u >> 16) & 1u)) >> 16);
}
__device__ __forceinline__ float bfu_lo(unsigned u) {
    union { unsigned u; float f; } v; v.u = u << 16; return v.f;
}
__device__ __forceinline__ float bfu_hi(unsigned u) {
    union { unsigned u; float f; } v; v.u = u & 0xffff0000u; return v.f;
}

// A_pk fragment-packed layout: tile t (64 rows), element (r, k):
//   ks=k>>5, lq=(k>>3)&3, j=k&7, mi=r>>4, lm=r&15
//   index = t*16384 + ((ks*4+mi)*64 + lm + 16*lq)*8 + j

// ---- merged setup + edge-partition ----
// blocks [0,196): pass A of CSR build (two-pass, no scratch)
// blocks [196,260): pack W1/W2 into MFMA B-fragment order
// blocks [260,6510): x -> fp8 gather table + A_pk self-columns (bf16, frag-packed)
__global__ void k_setup_part(const float* __restrict__ W1l, const float* __restrict__ W1r,
                             const float* __restrict__ W2l, const float* __restrict__ W2r,
                             unsigned short* __restrict__ W1pk, unsigned short* __restrict__ W2pk,
                             const float4* __restrict__ x4, unsigned short* __restrict__ Apk,
                             unsigned char* __restrict__ x_f8,
                             const int* __restrict__ src, const int* __restrict__ dst,
                             int* __restrict__ gcursor, unsigned* __restrict__ pairs) {
    int blk = blockIdx.x, t = threadIdx.x;
    if (blk < NB) {
        __shared__ int cnt[256];
        __shared__ int cur[256];
        __shared__ int base[256];
        cnt[t] = 0; cur[t] = 0;
        __syncthreads();
        int e0 = blk * EPB;
        int eend = min(e0 + EPB, NE);
        for (int e = e0 + t; e < eend; e += 256)
            atomicAdd(&cnt[dst[e] >> 8], 1);
        __syncthreads();
        if (t < NB && cnt[t] > 0) base[t] = t * CAP + atomicAdd(&gcursor[t], cnt[t]);
        __syncthreads();
        for (int e = e0 + t; e < eend; e += 256) {
            int s = src[e], d = dst[e];
            int bk = d >> 8;
            int pos = base[bk] + atomicAdd(&cur[bk], 1);
            if (pos < (bk + 1) * CAP) pairs[pos] = ((unsigned)s << 8) | (unsigned)(d & 255);
        }
    } else if (blk < 260) {
        int tid = (blk - 196) * 256 + t;    // 0..16383
        int table = tid >> 13;              // 0: W1, 1: W2
        int r = tid & 8191;
        int lane = r & 63, ni = (r >> 6) & 3, ks = (r >> 8) & 7, g = r >> 11;
        int lm = lane & 15, lq = lane >> 4;
        int o = g * 64 + ni * 16 + lm;
        int k = ks * 32 + lq * 8;
        unsigned short v[8];
        if (table == 0) {                   // W1 = [W1l | W1r] K-concat
            if (k < 128) {
#pragma unroll
                for (int j = 0; j < 8; ++j) v[j] = f2bf(W1l[o * 128 + k + j]);
            } else {
#pragma unroll
                for (int j = 0; j < 8; ++j) v[j] = f2bf(W1r[o * 128 + k - 128 + j]);
            }
            *(uint4*)(W1pk + (size_t)r * 8) = *(const uint4*)v;
        } else {                            // W2 = [W2l ; W2r] out-stack
            if (o < 128) {
#pragma unroll
                for (int j = 0; j < 8; ++j) v[j] = f2bf(W2l[o * 256 + k + j]);
            } else {
#pragma unroll
                for (int j = 0; j < 8; ++j) v[j] = f2bf(W2r[(o - 128) * 256 + k + j]);
            }
            *(uint4*)(W2pk + (size_t)r * 8) = *(const uint4*)v;
        }
    } else {
        int gid = (blk - 260) * 256 + t;    // NN*32
        int n = gid >> 5, c = gid & 31;     // self cols k = 128 + c*4 .. +3
        float4 v = x4[(size_t)n * 32 + c];
        unsigned short o[4];
        o[0] = f2bf(v.x); o[1] = f2bf(v.y); o[2] = f2bf(v.z); o[3] = f2bf(v.w);
        int k = 128 + c * 4;
        int ks = k >> 5, lq = (k >> 3) & 3, j0 = k & 7;
        int tile = n >> 6, r = n & 63, mi = r >> 4, lm = r & 15;
        *(uint2*)(Apk + (size_t)tile * 16384 +
                  ((size_t)((ks * 4 + mi) * 64 + lm + 16 * lq)) * 8 + j0) = *(const uint2*)o;
        unsigned p = (unsigned)__builtin_amdgcn_cvt_pk_fp8_f32(v.x, v.y, 0, false);
        p = (unsigned)__builtin_amdgcn_cvt_pk_fp8_f32(v.z, v.w, (int)p, true);
        *(unsigned*)(x_f8 + (size_t)n * 128 + c * 4) = p;
    }
}

// ---- pass B: scan bucket counts + per-bucket LDS counting sort, two-pass ----
// meta[n] = row_start | (deg << 20); esrc is ushort.
__global__ void k_build(const int* __restrict__ gcursor, const unsigned* __restrict__ pairs,
                        unsigned* __restrict__ meta, unsigned short* __restrict__ esrc) {
    __shared__ int buf[256];
    __shared__ int ldeg[256];
    __shared__ int cur[256];
    __shared__ int sh_base, sh_cnt;
    __shared__ unsigned short lsrc[CAP];
    int b = blockIdx.x, t = threadIdx.x;
    int c = (t < NB) ? min(gcursor[t], CAP) : 0;
    buf[t] = c;
    __syncthreads();
#pragma unroll
    for (int o = 1; o < 256; o <<= 1) {
        int add = (t >= o) ? buf[t - o] : 0;
        __syncthreads();
        buf[t] += add;
        __syncthreads();
    }
    if (t == b) { sh_cnt = c; sh_base = buf[b] - c; }
    ldeg[t] = 0;
    __syncthreads();
    int cnt = sh_cnt, base = sh_base;
    for (int e = t; e < cnt; e += 256)
        atomicAdd(&ldeg[pairs[(size_t)b * CAP + e] & 255u], 1);
    __syncthreads();
    int v = ldeg[t];
    buf[t] = v;
    __syncthreads();
#pragma unroll
    for (int o = 1; o < 256; o <<= 1) {
        int add = (t >= o) ? buf[t - o] : 0;
        __syncthreads();
        buf[t] += add;
        __syncthreads();
    }
    int lst = buf[t] - v;
    cur[t] = lst;
    int node = b * 256 + t;
    meta[node] = (node < NN) ? ((unsigned)(base + lst) | ((unsigned)v << 20)) : 0u;
    __syncthreads();
    for (int e = t; e < cnt; e += 256) {
        unsigned p = pairs[(size_t)b * CAP + e];
        int pos = atomicAdd(&cur[p & 255u], 1);
        lsrc[pos] = (unsigned short)(p >> 8);
    }
    __syncthreads();
    for (int e = t; e < cnt; e += 256) esrc[base + e] = lsrc[e];
}

// ============ layer-1 aggregation -> A_pk cols 0..127 (fragment-packed) ============
__global__ void k_agg1(const uint2* __restrict__ xf8, const unsigned* __restrict__ meta,
                       const unsigned short* __restrict__ esrc,
                       unsigned short* __restrict__ Apk) {
    int gid = blockIdx.x * blockDim.x + threadIdx.x;  // NN*16 threads exactly
    int n = gid >> 4, c = gid & 15;                   // cols k = c*8 .. +7
    unsigned mt = meta[n];
    int st = (int)(mt & 0xFFFFFu), dg = (int)(mt >> 20);
    float acc[8] = {0.f, 0.f, 0.f, 0.f, 0.f, 0.f, 0.f, 0.f};
    int i = 0;
    for (; i + 2 <= dg; i += 2) {
        int s0 = esrc[st + i], s1 = esrc[st + i + 1];
        uint2 q0 = xf8[(size_t)s0 * 16 + c];
        uint2 q1 = xf8[(size_t)s1 * 16 + c];
        f32x2 a0 = __builtin_amdgcn_cvt_pk_f32_fp8(q0.x, false);
        f32x2 a1 = __builtin_amdgcn_cvt_pk_f32_fp8(q0.x, true);
        f32x2 a2 = __builtin_amdgcn_cvt_pk_f32_fp8(q0.y, false);
        f32x2 a3 = __builtin_amdgcn_cvt_pk_f32_fp8(q0.y, true);
        f32x2 b0 = __builtin_amdgcn_cvt_pk_f32_fp8(q1.x, false);
        f32x2 b1 = __builtin_amdgcn_cvt_pk_f32_fp8(q1.x, true);
        f32x2 b2 = __builtin_amdgcn_cvt_pk_f32_fp8(q1.y, false);
        f32x2 b3 = __builtin_amdgcn_cvt_pk_f32_fp8(q1.y, true);
        acc[0] += a0.x + b0.x; acc[1] += a0.y + b0.y;
        acc[2] += a1.x + b1.x; acc[3] += a1.y + b1.y;
        acc[4] += a2.x + b2.x; acc[5] += a2.y + b2.y;
        acc[6] += a3.x + b3.x; acc[7] += a3.y + b3.y;
    }
    if (i < dg) {
        int s = esrc[st + i];
        uint2 q0 = xf8[(size_t)s * 16 + c];
        f32x2 a0 = __builtin_amdgcn_cvt_pk_f32_fp8(q0.x, false);
        f32x2 a1 = __builtin_amdgcn_cvt_pk_f32_fp8(q0.x, true);
        f32x2 a2 = __builtin_amdgcn_cvt_pk_f32_fp8(q0.y, false);
        f32x2 a3 = __builtin_amdgcn_cvt_pk_f32_fp8(q0.y, true);
        acc[0] += a0.x; acc[1] += a0.y;
        acc[2] += a1.x; acc[3] += a1.y;
        acc[4] += a2.x; acc[5] += a2.y;
        acc[6] += a3.x; acc[7] += a3.y;
    }
    float invd = 1.0f / (float)max(dg, 1);
    unsigned short o[8];
#pragma unroll
    for (int j = 0; j < 8; ++j) o[j] = f2bf(acc[j] * invd);
    int ks = c >> 2, lq = c & 3;
    int tile = n >> 6, r = n & 63, mi = r >> 4, lm = r & 15;
    *(uint4*)(Apk + (size_t)tile * 16384 +
              ((size_t)((ks * 4 + mi) * 64 + lm + 16 * lq)) * 8) = *(const uint4*)o;
}

// ============ fused GEMM1(relu)+GEMM2 per 64-node tile, packed-A direct reads ============
// A_pk fragment-packed: wave A-loads are 1 KB coalesced global loads (L2-hot).
// W in VGPRs (32 short8 = 128 regs/wave, loaded once per layer).
// h LDS tile T: element (m, k) at chunk (ks*4+mi)*64 + lm*4 + lq.
// Epilogue bounces through T (dead after GEMM2) so global stores are
// line-complete 16 B/lane contiguous — kills write-allocate amplification.
__global__ __launch_bounds__(256, 2) void k_gemm12(
        const unsigned short* __restrict__ Apk,
        const unsigned short* __restrict__ W1pk, const unsigned short* __restrict__ W2pk,
        const float* __restrict__ b1, const float* __restrict__ b2,
        unsigned char* __restrict__ y2f8, unsigned short* __restrict__ Sbf) {
    __shared__ unsigned short T[16384];   // 32 KB: h tile, then epilogue staging
    int t = threadIdx.x, blk = blockIdx.x;
    int wave = t >> 6, lane = t & 63;
    int lm = lane & 15, lq = lane >> 4;
    int pbase = lm * 4 + lq;

    // ---- preload W1 slice into registers ----
    short8 w[8][4];
    {
        const unsigned short* wb = W1pk + (size_t)wave * 16384;
#pragma unroll
        for (int ks = 0; ks < 8; ++ks)
#pragma unroll
            for (int ni = 0; ni < 4; ++ni)
                w[ks][ni] = *(const short8*)(wb + ((size_t)((ks * 4 + ni) * 64 + lane)) * 8);
    }

    // ---- GEMM1: A direct from packed global (coalesced) ----
    const unsigned short* apk = Apk + (size_t)blk * 16384;
    f32x4 acc1[4][4];
#pragma unroll
    for (int mi = 0; mi < 4; ++mi)
#pragma unroll
        for (int ni = 0; ni < 4; ++ni) acc1[mi][ni] = (f32x4){0.f, 0.f, 0.f, 0.f};
#pragma unroll
    for (int ks = 0; ks < 8; ++ks) {
        short8 a[4];
#pragma unroll
        for (int mi = 0; mi < 4; ++mi)
            a[mi] = *(const short8*)(apk + ((size_t)((ks * 4 + mi) * 64 + lane)) * 8);
#pragma unroll
        for (int mi = 0; mi < 4; ++mi)
#pragma unroll
            for (int ni = 0; ni < 4; ++ni)
                acc1[mi][ni] = __builtin_amdgcn_mfma_f32_16x16x32_bf16(a[mi], w[ks][ni], acc1[mi][ni], 0, 0, 0);
    }

    // ---- reload registers with W2 slice (latency hidden by h-write) ----
    {
        const unsigned short* wb = W2pk + (size_t)wave * 16384;
#pragma unroll
        for (int ks = 0; ks < 8; ++ks)
#pragma unroll
            for (int ni = 0; ni < 4; ++ni)
                w[ks][ni] = *(const short8*)(wb + ((size_t)((ks * 4 + ni) * 64 + lane)) * 8);
    }

    // ---- h = relu(acc1 + b1) into T (fragment order; per-wave disjoint chunks) ----
#pragma unroll
    for (int ni = 0; ni < 4; ++ni) {
        int col = wave * 64 + ni * 16 + lm;
        float bv = b1[col];
        int ks = col >> 5;
        int la = (col & 31) >> 3, j = col & 7;
#pragma unroll
        for (int mi = 0; mi < 4; ++mi)
#pragma unroll
            for (int r = 0; r < 4; ++r) {
                float v = fmaxf(acc1[mi][ni][r] + bv, 0.0f);
                T[((size_t)((ks * 4 + mi) * 64 + (lq * 4 + r) * 4 + la)) * 8 + j] = f2bf(v);
            }
    }
    __syncthreads();

    // ---- GEMM2 ----
    f32x4 acc2[4][4];
#pragma unroll
    for (int mi = 0; mi < 4; ++mi)
#pragma unroll
        for (int ni = 0; ni < 4; ++ni) acc2[mi][ni] = (f32x4){0.f, 0.f, 0.f, 0.f};
#pragma unroll
    for (int ks = 0; ks < 8; ++ks) {
        short8 a[4];
#pragma unroll
        for (int mi = 0; mi < 4; ++mi)
            a[mi] = *(const short8*)(T + ((size_t)((ks * 4 + mi) * 64 + pbase)) * 8);
#pragma unroll
        for (int mi = 0; mi < 4; ++mi)
#pragma unroll
            for (int ni = 0; ni < 4; ++ni)
                acc2[mi][ni] = __builtin_amdgcn_mfma_f32_16x16x32_bf16(a[mi], w[ks][ni], acc2[mi][ni], 0, 0, 0);
    }
    __syncthreads();   // all GEMM2 reads of T done; T is now epilogue staging

    // ---- epilogue phase 1: stage tiles in T row-major ----
    // T bytes [0,8192): y2 fp8 tile 64x128; [8192,24576): Sbf bf16 tile 64x128
    {
        unsigned char* T8 = (unsigned char*)T;
        unsigned short* T16 = (unsigned short*)T + 4096;
        if (wave < 2) {
#pragma unroll
            for (int ni = 0; ni < 4; ++ni) {
                int col = wave * 64 + ni * 16 + lm;
#pragma unroll
                for (int mi = 0; mi < 4; ++mi)
#pragma unroll
                    for (int r = 0; r < 4; ++r) {
                        int rl = mi * 16 + lq * 4 + r;
                        float v = acc2[mi][ni][r];
                        unsigned p = (unsigned)__builtin_amdgcn_cvt_pk_fp8_f32(v, v, 0, false);
                        T8[rl * 128 + col] = (unsigned char)(p & 0xff);
                    }
            }
        } else {
#pragma unroll
            for (int ni = 0; ni < 4; ++ni) {
                int col = (wave - 2) * 64 + ni * 16 + lm;
                float bv = b2[col];
#pragma unroll
                for (int mi = 0; mi < 4; ++mi)
#pragma unroll
                    for (int r = 0; r < 4; ++r) {
                        int rl = mi * 16 + lq * 4 + r;
                        T16[rl * 128 + col] = f2bf(acc2[mi][ni][r] + bv);
                    }
            }
        }
    }
    __syncthreads();

    // ---- epilogue phase 2: contiguous line-complete global stores ----
    {
        const uint4* Ty = (const uint4*)T;                       // 512 uint4 (8 KB)
        uint4* gy = (uint4*)(y2f8 + (size_t)blk * 64 * 128);     // tile contiguous
        gy[t] = Ty[t];
        gy[t + 256] = Ty[t + 256];
        const uint4* Ts = (const uint4*)((const char*)T + 8192); // 1024 uint4 (16 KB)
        uint4* gs = (uint4*)(Sbf + (size_t)blk * 64 * 128);      // tile contiguous
#pragma unroll
        for (int i = 0; i < 4; ++i) gs[t + i * 256] = Ts[t + i * 256];
    }
}

// ============ output: out[n] = Sbf[n] + mean_nbr(y2f8)  (pure write) ============
__global__ void k_agg_out(const uint2* __restrict__ yf8, const uint4* __restrict__ Sbf4,
                          const unsigned* __restrict__ meta,
                          const unsigned short* __restrict__ esrc,
                          float* __restrict__ out) {
    int gid = blockIdx.x * blockDim.x + threadIdx.x;  // NN*16 threads exactly
    int n = gid >> 4, c = gid & 15;
    unsigned mt = meta[n];
    int st = (int)(mt & 0xFFFFFu), dg = (int)(mt >> 20);
    float acc[8] = {0.f, 0.f, 0.f, 0.f, 0.f, 0.f, 0.f, 0.f};
    int i = 0;
    for (; i + 2 <= dg; i += 2) {
        int s0 = esrc[st + i], s1 = esrc[st + i + 1];
        uint2 q0 = yf8[(size_t)s0 * 16 + c];
        uint2 q1 = yf8[(size_t)s1 * 16 + c];
        f32x2 a0 = __builtin_amdgcn_cvt_pk_f32_fp8(q0.x, false);
        f32x2 a1 = __builtin_amdgcn_cvt_pk_f32_fp8(q0.x, true);
        f32x2 a2 = __builtin_amdgcn_cvt_pk_f32_fp8(q0.y, false);
        f32x2 a3 = __builtin_amdgcn_cvt_pk_f32_fp8(q0.y, true);
        f32x2 b0 = __builtin_amdgcn_cvt_pk_f32_fp8(q1.x, false);
        f32x2 b1 = __builtin_amdgcn_cvt_pk_f32_fp8(q1.x, true);
        f32x2 b2 = __builtin_amdgcn_cvt_pk_f32_fp8(q1.y, false);
        f32x2 b3 = __builtin_amdgcn_cvt_pk_f32_fp8(q1.y, true);
        acc[0] += a0.x + b0.x; acc[1] += a0.y + b0.y;
        acc[2] += a1.x + b1.x; acc[3] += a1.y + b1.y;
        acc[4] += a2.x + b2.x; acc[5] += a2.y + b2.y;
        acc[6] += a3.x + b3.x; acc[7] += a3.y + b3.y;
    }
    if (i < dg) {
        int s = esrc[st + i];
        uint2 q0 = yf8[(size_t)s * 16 + c];
        f32x2 a0 = __builtin_amdgcn_cvt_pk_f32_fp8(q0.x, false);
        f32x2 a1 = __builtin_amdgcn_cvt_pk_f32_fp8(q0.x, true);
        f32x2 a2 = __builtin_amdgcn_cvt_pk_f32_fp8(q0.y, false);
        f32x2 a3 = __builtin_amdgcn_cvt_pk_f32_fp8(q0.y, true);
        acc[0] += a0.x; acc[1] += a0.y;
        acc[2] += a1.x; acc[3] += a1.y;
        acc[4] += a2.x; acc[5] += a2.y;
        acc[6] += a3.x; acc[7] += a3.y;
    }
    float invd = 1.0f / (float)max(dg, 1);
    uint4 sv = Sbf4[(size_t)n * 16 + c];
    float4 o0, o1;
    o0.x = bfu_lo(sv.x) + acc[0] * invd; o0.y = bfu_hi(sv.x) + acc[1] * invd;
    o0.z = bfu_lo(sv.y) + acc[2] * invd; o0.w = bfu_hi(sv.y) + acc[3] * invd;
    o1.x = bfu_lo(sv.z) + acc[4] * invd; o1.y = bfu_hi(sv.z) + acc[5] * invd;
    o1.z = bfu_lo(sv.w) + acc[6] * invd; o1.w = bfu_hi(sv.w) + acc[7] * invd;
    float* op = out + (size_t)n * 128 + c * 8;
    *(float4*)op = o0; *(float4*)(op + 4) = o1;
}

extern "C" void kernel_launch(void* const* d_in, const int* in_sizes, int n_in,
                              void* d_out, int out_size, void* d_ws, size_t ws_size,
                              hipStream_t stream) {
    const float* x   = (const float*)d_in[0];
    const int*   ei  = (const int*)d_in[1];
    const int*   src = ei;
    const int*   dst = ei + NE;
    const float* W1l = (const float*)d_in[2];
    const float* b1  = (const float*)d_in[3];
    const float* W1r = (const float*)d_in[4];
    const float* W2l = (const float*)d_in[5];
    const float* b2  = (const float*)d_in[6];
    const float* W2r = (const float*)d_in[7];
    float* out = (float*)d_out;

    // workspace layout (~62 MB):
    char* ws = (char*)d_ws;
    unsigned* meta        = (unsigned*)(ws + 0);               // [NN_PAD] start|deg<<20
    int* gcursor          = (int*)(ws + 401408);               // [256]
    unsigned short* esrc  = (unsigned short*)(ws + 409600);    // [NE] ushort 1.6 MB
    unsigned* pairs       = (unsigned*)(ws + 4194304);         // [NB*CAP] 4.8 MB
    unsigned short* Sbf   = (unsigned short*)(ws + 9437184);   // [NN_PAD,128] bf16 12.85 MB
    unsigned char* x_f8   = (unsigned char*)(ws + 22282240);   // [NN,128] fp8 6.4 MB
    unsigned char* y2f8   = (unsigned char*)(ws + 28704768);   // [NN_PAD,128] fp8 6.42 MB
    unsigned short* Apk   = (unsigned short*)(ws + 35651584);  // [NN_PAD,256] bf16 frag-packed
    unsigned short* W1pk  = (unsigned short*)(ws + 61341696);  // [65536] 131 KB frag-packed
    unsigned short* W2pk  = (unsigned short*)(ws + 61472768);  // [65536] 131 KB frag-packed

    hipMemsetAsync(gcursor, 0, 1024, stream);
    k_setup_part<<<6510, 256, 0, stream>>>(W1l, W1r, W2l, W2r, W1pk, W2pk,
                                           (const float4*)x, Apk, x_f8, src, dst,
                                           gcursor, pairs);
    k_build<<<NB, 256, 0, stream>>>(gcursor, pairs, meta, esrc);
    k_agg1<<<NN * 16 / 256, 256, 0, stream>>>((const uint2*)x_f8, meta, esrc, Apk);
    k_gemm12<<<NN_PAD / 64, 256, 0, stream>>>(Apk, W1pk, W2pk, b1, b2, y2f8, Sbf);
    k_agg_out<<<NN * 16 / 256, 256, 0, stream>>>((const uint2*)y2f8, (const uint4*)Sbf,
                                                 meta, esrc, out);
}